// Round 1
// baseline (141.833 us; speedup 1.0000x reference)
//
#include <hip/hip_runtime.h>

#define BB 8
#define NN 8192
#define MM 8192
#define SPLIT 8
#define MCHUNK (MM / SPLIT)  // 1024

// ws layout:
//   [0, 512KB)          : float4 packed[B*M]   = (x, y, z, x^2+y^2+z^2) of xyz2
//   [512KB, 512KB+2MB)  : float  pmins[SPLIT*B*N]  partial mins per M-split
#define PACKED_OFF 0
#define PMINS_OFF (BB * MM * 16)

__global__ __launch_bounds__(256) void chamfer_pack(const float* __restrict__ xyz2,
                                                    float4* __restrict__ packed) {
    int idx = blockIdx.x * 256 + threadIdx.x;  // 0 .. B*M-1
    float x = xyz2[idx * 3 + 0];
    float y = xyz2[idx * 3 + 1];
    float z = xyz2[idx * 3 + 2];
    packed[idx] = make_float4(x, y, z, fmaf(x, x, fmaf(y, y, z * z)));
}

__global__ __launch_bounds__(256) void chamfer_min(const float* __restrict__ xyz1,
                                                   const float4* __restrict__ packed,
                                                   float* __restrict__ pmins) {
    // blockIdx.x in [0, 2048): low 8 bits = (batch, ntile), high 3 bits = m-split
    int tile  = blockIdx.x & 255;
    int split = blockIdx.x >> 8;
    int batch = tile >> 5;   // 8 batches
    int ntile = tile & 31;   // 32 tiles of 256 points
    int i = (ntile << 8) + threadIdx.x;

    const float* p1 = xyz1 + ((size_t)batch * NN + i) * 3;
    float ax = p1[0], ay = p1[1], az = p1[2];
    float x2 = fmaf(ax, ax, fmaf(ay, ay, az * az));
    // d_j = x2 + (y2_j - 2*x.y_j); fold x2 out of the loop.
    float bx = -2.0f * ax, by = -2.0f * ay, bz = -2.0f * az;

    const float4* pk = packed + (size_t)batch * MM + (size_t)split * MCHUNK;

    float m0 = 1e30f, m1 = 1e30f, m2 = 1e30f, m3 = 1e30f;
#pragma unroll 4
    for (int j = 0; j < MCHUNK; j += 4) {
        float4 w0 = pk[j + 0];
        float4 w1 = pk[j + 1];
        float4 w2 = pk[j + 2];
        float4 w3 = pk[j + 3];
        m0 = fminf(m0, fmaf(bx, w0.x, fmaf(by, w0.y, fmaf(bz, w0.z, w0.w))));
        m1 = fminf(m1, fmaf(bx, w1.x, fmaf(by, w1.y, fmaf(bz, w1.z, w1.w))));
        m2 = fminf(m2, fmaf(bx, w2.x, fmaf(by, w2.y, fmaf(bz, w2.z, w2.w))));
        m3 = fminf(m3, fmaf(bx, w3.x, fmaf(by, w3.y, fmaf(bz, w3.z, w3.w))));
    }
    float m = fminf(fminf(m0, m1), fminf(m2, m3));
    pmins[(size_t)split * (BB * NN) + (size_t)batch * NN + i] = x2 + m;
}

__global__ __launch_bounds__(256) void chamfer_reduce(const float* __restrict__ pmins,
                                                      float* __restrict__ out) {
    // 64 blocks * 256 threads; each thread handles 4 points
    int idx = blockIdx.x * 256 + threadIdx.x;
    float s = 0.0f;
#pragma unroll
    for (int r = 0; r < 4; ++r) {
        int p = idx + r * 16384;
        float m = pmins[p];
#pragma unroll
        for (int sp = 1; sp < SPLIT; ++sp)
            m = fminf(m, pmins[(size_t)sp * (BB * NN) + p]);
        s += m;
    }
    // wave-64 shuffle reduction
#pragma unroll
    for (int off = 32; off > 0; off >>= 1) s += __shfl_down(s, off);
    __shared__ float ls[4];
    int lane = threadIdx.x & 63, wv = threadIdx.x >> 6;
    if (lane == 0) ls[wv] = s;
    __syncthreads();
    if (threadIdx.x == 0) {
        float t = (ls[0] + ls[1]) + (ls[2] + ls[3]);
        atomicAdd(out, t * (1.0f / (float)(BB * NN)));
    }
}

extern "C" void kernel_launch(void* const* d_in, const int* in_sizes, int n_in,
                              void* d_out, int out_size, void* d_ws, size_t ws_size,
                              hipStream_t stream) {
    const float* xyz1 = (const float*)d_in[0];
    const float* xyz2 = (const float*)d_in[1];
    float* out = (float*)d_out;
    float4* packed = (float4*)((char*)d_ws + PACKED_OFF);
    float* pmins = (float*)((char*)d_ws + PMINS_OFF);

    hipMemsetAsync(out, 0, sizeof(float), stream);
    chamfer_pack<<<(BB * MM) / 256, 256, 0, stream>>>(xyz2, packed);
    chamfer_min<<<BB * (NN / 256) * SPLIT, 256, 0, stream>>>(xyz1, packed, pmins);
    chamfer_reduce<<<(BB * NN) / (256 * 4), 256, 0, stream>>>(pmins, out);
}

// Round 2
// 127.645 us; speedup vs baseline: 1.1111x; 1.1111x over previous
//
#include <hip/hip_runtime.h>

#define BB 8
#define NN 8192
#define MM 8192
#define SPLIT 8
#define MCHUNK (MM / SPLIT)  // 1024
#define P 4                  // xyz1 points per thread in chamfer_min

// ws layout:
//   [0, 512KB)          : float4 packed[B*M]      = (x, y, z, |y|^2) of xyz2
//   [512KB, 512KB+2MB)  : float  pmins[SPLIT*B*N]  partial mins per M-split
#define PACKED_OFF 0
#define PMINS_OFF (BB * MM * 16)

__global__ __launch_bounds__(256) void chamfer_pack(const float* __restrict__ xyz2,
                                                    float4* __restrict__ packed,
                                                    float* __restrict__ out) {
    if (blockIdx.x == 0 && threadIdx.x == 0) out[0] = 0.0f;  // zero accumulator (replaces memset node)
    int idx = blockIdx.x * 256 + threadIdx.x;  // 0 .. B*M-1
    float x = xyz2[idx * 3 + 0];
    float y = xyz2[idx * 3 + 1];
    float z = xyz2[idx * 3 + 2];
    packed[idx] = make_float4(x, y, z, fmaf(x, x, fmaf(y, y, z * z)));
}

__global__ __launch_bounds__(256) void chamfer_min(const float4* __restrict__ xyz1f4,
                                                   const float4* __restrict__ packed,
                                                   float4* __restrict__ pmins4) {
    // 512 blocks: low 6 bits = tile over B*N (64 tiles x 1024 points), high 3 = m-split
    int tile  = blockIdx.x & 63;
    int split = blockIdx.x >> 6;
    int batch = tile >> 3;   // 8 batches
    int nt    = tile & 7;    // 8 tiles of 1024 points per batch
    int g = nt * 256 + threadIdx.x;  // 4-point group index within batch, 0..2047

    // load this thread's 4 xyz1 points (12 floats = 3 float4, coalesced-ish, one-time)
    const float4* q = xyz1f4 + (size_t)batch * (NN * 3 / 4) + 3 * (size_t)g;
    float4 q0 = q[0], q1 = q[1], q2 = q[2];
    float px[P] = {q0.x, q0.w, q1.z, q2.y};
    float py[P] = {q0.y, q1.x, q1.w, q2.z};
    float pz[P] = {q0.z, q1.y, q2.x, q2.w};
    float bx[P], by[P], bz[P], x2[P], m[P];
#pragma unroll
    for (int p = 0; p < P; ++p) {
        x2[p] = fmaf(px[p], px[p], fmaf(py[p], py[p], pz[p] * pz[p]));
        bx[p] = -2.0f * px[p];
        by[p] = -2.0f * py[p];
        bz[p] = -2.0f * pz[p];
        m[p] = 1e30f;
    }

    // wave-uniform pointer -> compiler scalarizes to s_load_dwordx4 (R1: VGPR=12/SGPR=96)
    const float4* pk = packed + (size_t)batch * MM + (size_t)split * MCHUNK;
#pragma unroll 8
    for (int j = 0; j < MCHUNK; ++j) {
        float4 w = pk[j];
#pragma unroll
        for (int p = 0; p < P; ++p)
            m[p] = fminf(m[p], fmaf(bx[p], w.x, fmaf(by[p], w.y, fmaf(bz[p], w.z, w.w))));
    }

    float4 r = make_float4(x2[0] + m[0], x2[1] + m[1], x2[2] + m[2], x2[3] + m[3]);
    pmins4[(size_t)split * (BB * NN / 4) + (size_t)batch * (NN / 4) + g] = r;
}

__global__ __launch_bounds__(256) void chamfer_reduce(const float4* __restrict__ pmins4,
                                                      float* __restrict__ out) {
    // 64 blocks * 256 threads; each thread handles one 4-point group
    int idx = blockIdx.x * 256 + threadIdx.x;  // 0..16383
    float4 m = pmins4[idx];
#pragma unroll
    for (int sp = 1; sp < SPLIT; ++sp) {
        float4 v = pmins4[(size_t)sp * (BB * NN / 4) + idx];
        m.x = fminf(m.x, v.x);
        m.y = fminf(m.y, v.y);
        m.z = fminf(m.z, v.z);
        m.w = fminf(m.w, v.w);
    }
    float s = (m.x + m.y) + (m.z + m.w);
    // wave-64 shuffle reduction
#pragma unroll
    for (int off = 32; off > 0; off >>= 1) s += __shfl_down(s, off);
    __shared__ float ls[4];
    int lane = threadIdx.x & 63, wv = threadIdx.x >> 6;
    if (lane == 0) ls[wv] = s;
    __syncthreads();
    if (threadIdx.x == 0) {
        float t = (ls[0] + ls[1]) + (ls[2] + ls[3]);
        atomicAdd(out, t * (1.0f / (float)(BB * NN)));
    }
}

extern "C" void kernel_launch(void* const* d_in, const int* in_sizes, int n_in,
                              void* d_out, int out_size, void* d_ws, size_t ws_size,
                              hipStream_t stream) {
    const float* xyz1 = (const float*)d_in[0];
    const float* xyz2 = (const float*)d_in[1];
    float* out = (float*)d_out;
    float4* packed = (float4*)((char*)d_ws + PACKED_OFF);
    float4* pmins4 = (float4*)((char*)d_ws + PMINS_OFF);

    chamfer_pack<<<(BB * MM) / 256, 256, 0, stream>>>(xyz2, packed, out);
    chamfer_min<<<(BB * NN / (P * 256)) * SPLIT, 256, 0, stream>>>((const float4*)xyz1, packed, pmins4);
    chamfer_reduce<<<(BB * NN) / (256 * 4), 256, 0, stream>>>(pmins4, out);
}

// Round 3
// 104.624 us; speedup vs baseline: 1.3557x; 1.2200x over previous
//
#include <hip/hip_runtime.h>

typedef float v2f __attribute__((ext_vector_type(2)));

#define BB 8
#define NN 8192
#define MM 8192
#define SPLIT 32
#define MCHUNK (MM / SPLIT)  // 256
#define P 8                  // xyz1 points per thread (4 float2 pairs)
#define NPAIR (P / 2)

// ws layout:
//   [0, 1MB)      : float4 packed[B*M] = (x, y, z, |y|^2) of xyz2
//   [1MB, 9MB)    : float pmins[SPLIT][B*N] partial mins per M-split
#define PACKED_OFF 0
#define PMINS_OFF (BB * MM * 16)

__global__ __launch_bounds__(256) void chamfer_pack(const float* __restrict__ xyz2,
                                                    float4* __restrict__ packed,
                                                    float* __restrict__ out) {
    if (blockIdx.x == 0 && threadIdx.x == 0) out[0] = 0.0f;  // zero accumulator
    int idx = blockIdx.x * 256 + threadIdx.x;  // 0 .. B*M-1
    float x = xyz2[idx * 3 + 0];
    float y = xyz2[idx * 3 + 1];
    float z = xyz2[idx * 3 + 2];
    packed[idx] = make_float4(x, y, z, fmaf(x, x, fmaf(y, y, z * z)));
}

__global__ __launch_bounds__(256, 4) void chamfer_min(const float4* __restrict__ xyz1f4,
                                                      const float4* __restrict__ packed,
                                                      float* __restrict__ pmins) {
    __shared__ float4 lds[MCHUNK];
    // grid = 32 tiles * 32 splits = 1024 blocks
    int tile  = blockIdx.x & 31;
    int split = blockIdx.x >> 5;
    int batch = tile >> 2;   // 8 batches
    int nt    = tile & 3;    // 4 tiles of 256 threads per batch
    int g = nt * 256 + threadIdx.x;  // this thread's 8-point group, 0..1023

    // stage this split's xyz2 chunk: one coalesced float4 per thread -> LDS
    lds[threadIdx.x] = packed[(size_t)batch * MM + (size_t)split * MCHUNK + threadIdx.x];

    // load this thread's 8 xyz1 points (24 floats = 6 float4)
    const float4* q = xyz1f4 + (size_t)batch * (NN * 3 / 4) + (size_t)g * 6;
    float f[24];
    float4* f4 = (float4*)f;
#pragma unroll
    for (int t = 0; t < 6; ++t) f4[t] = q[t];

    v2f bx[NPAIR], by[NPAIR], bz[NPAIR], x2[NPAIR], m[NPAIR];
#pragma unroll
    for (int pp = 0; pp < NPAIR; ++pp) {
        float ax0 = f[6 * pp + 0], ay0 = f[6 * pp + 1], az0 = f[6 * pp + 2];
        float ax1 = f[6 * pp + 3], ay1 = f[6 * pp + 4], az1 = f[6 * pp + 5];
        bx[pp] = (v2f){-2.0f * ax0, -2.0f * ax1};
        by[pp] = (v2f){-2.0f * ay0, -2.0f * ay1};
        bz[pp] = (v2f){-2.0f * az0, -2.0f * az1};
        x2[pp] = (v2f){fmaf(ax0, ax0, fmaf(ay0, ay0, az0 * az0)),
                       fmaf(ax1, ax1, fmaf(ay1, ay1, az1 * az1))};
        m[pp] = (v2f){1e30f, 1e30f};
    }

    __syncthreads();

    // broadcast ds_read_b128 per j (in-order -> compiler pipelines with partial lgkmcnt)
#pragma unroll 4
    for (int j = 0; j < MCHUNK; ++j) {
        float4 w = lds[j];
        v2f wx = {w.x, w.x}, wy = {w.y, w.y}, wz = {w.z, w.z}, ww = {w.w, w.w};
#pragma unroll
        for (int pp = 0; pp < NPAIR; ++pp) {
            v2f d = __builtin_elementwise_fma(bx[pp], wx,
                      __builtin_elementwise_fma(by[pp], wy,
                        __builtin_elementwise_fma(bz[pp], wz, ww)));
            m[pp] = __builtin_elementwise_min(m[pp], d);
        }
    }

    size_t base = (size_t)split * (BB * NN) + (size_t)batch * NN + (size_t)g * 8;
    float4 r0, r1;
    r0.x = x2[0].x + m[0].x; r0.y = x2[0].y + m[0].y;
    r0.z = x2[1].x + m[1].x; r0.w = x2[1].y + m[1].y;
    r1.x = x2[2].x + m[2].x; r1.y = x2[2].y + m[2].y;
    r1.z = x2[3].x + m[3].x; r1.w = x2[3].y + m[3].y;
    float4* dst = (float4*)(pmins + base);
    dst[0] = r0;
    dst[1] = r1;
}

__global__ __launch_bounds__(256) void chamfer_reduce(const float* __restrict__ pmins,
                                                      float* __restrict__ out) {
    int i = blockIdx.x * 256 + threadIdx.x;  // 0..65535, grid 256 blocks
    float m = pmins[i];
#pragma unroll
    for (int sp = 1; sp < SPLIT; ++sp)
        m = fminf(m, pmins[(size_t)sp * (BB * NN) + i]);
    float s = m;
#pragma unroll
    for (int off = 32; off > 0; off >>= 1) s += __shfl_down(s, off);
    __shared__ float ls[4];
    int lane = threadIdx.x & 63, wv = threadIdx.x >> 6;
    if (lane == 0) ls[wv] = s;
    __syncthreads();
    if (threadIdx.x == 0) {
        float t = (ls[0] + ls[1]) + (ls[2] + ls[3]);
        atomicAdd(out, t * (1.0f / (float)(BB * NN)));
    }
}

extern "C" void kernel_launch(void* const* d_in, const int* in_sizes, int n_in,
                              void* d_out, int out_size, void* d_ws, size_t ws_size,
                              hipStream_t stream) {
    const float* xyz1 = (const float*)d_in[0];
    const float* xyz2 = (const float*)d_in[1];
    float* out = (float*)d_out;
    float4* packed = (float4*)((char*)d_ws + PACKED_OFF);
    float* pmins = (float*)((char*)d_ws + PMINS_OFF);

    chamfer_pack<<<(BB * MM) / 256, 256, 0, stream>>>(xyz2, packed, out);
    chamfer_min<<<(BB * NN / (P * 256)) * SPLIT, 256, 0, stream>>>((const float4*)xyz1, packed, pmins);
    chamfer_reduce<<<(BB * NN) / 256, 256, 0, stream>>>(pmins, out);
}

// Round 4
// 100.134 us; speedup vs baseline: 1.4164x; 1.0448x over previous
//
#include <hip/hip_runtime.h>

typedef float v2f __attribute__((ext_vector_type(2)));
typedef float v4f __attribute__((ext_vector_type(4)));

#define BB 8
#define NN 8192
#define MM 8192
#define SPLIT 32
#define MCHUNK (MM / SPLIT)  // 256 xyz2 points staged per block
#define P 8                  // xyz1 points per thread

// ws layout: [0, 8MB) : float pmins[SPLIT][B*N]
__global__ __launch_bounds__(256, 4) void chamfer_min(const float* __restrict__ xyz1,
                                                      const float* __restrict__ xyz2,
                                                      float* __restrict__ pmins,
                                                      float* __restrict__ out) {
    if (blockIdx.x == 0 && threadIdx.x == 0) out[0] = 0.0f;  // reduce runs after; safe

    // SoA LDS: ds_read_b128 of xs[j..j+3] gives clean VGPR pairs (no splat movs)
    __shared__ float xs[MCHUNK], ys[MCHUNK], zs[MCHUNK], w2[MCHUNK];

    // grid = 1024: low 5 bits = tile over B*N (32 tiles x 2048 pts), high 5 = m-split
    int tile  = blockIdx.x & 31;
    int split = blockIdx.x >> 5;
    int batch = tile >> 2;   // 8 batches
    int nt    = tile & 3;    // 4 tiles of 2048 points per batch
    int g = nt * 256 + threadIdx.x;  // this thread's 8-point group, 0..1023

    // ---- fused pack: stage this split's xyz2 chunk raw -> LDS SoA ----
    {
        int t = threadIdx.x;
        size_t pj = (size_t)batch * MM + (size_t)split * MCHUNK + t;
        float x = xyz2[pj * 3 + 0];
        float y = xyz2[pj * 3 + 1];
        float z = xyz2[pj * 3 + 2];
        xs[t] = x; ys[t] = y; zs[t] = z;
        w2[t] = fmaf(x, x, fmaf(y, y, z * z));
    }

    // ---- load this thread's 8 xyz1 points (24 floats = 6 float4) ----
    const float4* q = (const float4*)(xyz1 + ((size_t)batch * NN + (size_t)g * P) * 3);
    float f[24];
    float4* f4 = (float4*)f;
#pragma unroll
    for (int t = 0; t < 6; ++t) f4[t] = q[t];

    v2f bx2[P], by2[P], bz2[P], m2[P];
    float x2[P];
#pragma unroll
    for (int p = 0; p < P; ++p) {
        float ax = f[3 * p + 0], ay = f[3 * p + 1], az = f[3 * p + 2];
        x2[p] = fmaf(ax, ax, fmaf(ay, ay, az * az));
        // loop-invariant splats (hoisted out of the j loop)
        bx2[p] = (v2f){-2.0f * ax, -2.0f * ax};
        by2[p] = (v2f){-2.0f * ay, -2.0f * ay};
        bz2[p] = (v2f){-2.0f * az, -2.0f * az};
        m2[p] = (v2f){1e30f, 1e30f};
    }

    __syncthreads();

    // ---- main loop: 4 j's per iteration via b128 SoA reads, pk-math over j-pairs ----
#pragma unroll 2
    for (int j = 0; j < MCHUNK; j += 4) {
        v4f wx = *(const v4f*)&xs[j];
        v4f wy = *(const v4f*)&ys[j];
        v4f wz = *(const v4f*)&zs[j];
        v4f ww = *(const v4f*)&w2[j];
        v2f wxl = {wx.x, wx.y}, wxh = {wx.z, wx.w};
        v2f wyl = {wy.x, wy.y}, wyh = {wy.z, wy.w};
        v2f wzl = {wz.x, wz.y}, wzh = {wz.z, wz.w};
        v2f wwl = {ww.x, ww.y}, wwh = {ww.z, ww.w};
#pragma unroll
        for (int p = 0; p < P; ++p) {
            v2f dl = __builtin_elementwise_fma(bx2[p], wxl,
                       __builtin_elementwise_fma(by2[p], wyl,
                         __builtin_elementwise_fma(bz2[p], wzl, wwl)));
            m2[p] = __builtin_elementwise_min(m2[p], dl);
            v2f dh = __builtin_elementwise_fma(bx2[p], wxh,
                       __builtin_elementwise_fma(by2[p], wyh,
                         __builtin_elementwise_fma(bz2[p], wzh, wwh)));
            m2[p] = __builtin_elementwise_min(m2[p], dh);
        }
    }

    // ---- epilogue: collapse pair mins, add x2, store 8 floats as 2 float4 ----
    float r[P];
#pragma unroll
    for (int p = 0; p < P; ++p) r[p] = x2[p] + fminf(m2[p].x, m2[p].y);
    size_t base = (size_t)split * (BB * NN) + (size_t)batch * NN + (size_t)g * P;
    float4* dst = (float4*)(pmins + base);
    dst[0] = ((float4*)r)[0];
    dst[1] = ((float4*)r)[1];
}

__global__ __launch_bounds__(256) void chamfer_reduce(const float* __restrict__ pmins,
                                                      float* __restrict__ out) {
    int i = blockIdx.x * 256 + threadIdx.x;  // grid 256 blocks, 0..65535
    float m = pmins[i];
#pragma unroll
    for (int sp = 1; sp < SPLIT; ++sp)
        m = fminf(m, pmins[(size_t)sp * (BB * NN) + i]);
    float s = m;
#pragma unroll
    for (int off = 32; off > 0; off >>= 1) s += __shfl_down(s, off);
    __shared__ float ls[4];
    int lane = threadIdx.x & 63, wv = threadIdx.x >> 6;
    if (lane == 0) ls[wv] = s;
    __syncthreads();
    if (threadIdx.x == 0) {
        float t = (ls[0] + ls[1]) + (ls[2] + ls[3]);
        atomicAdd(out, t * (1.0f / (float)(BB * NN)));
    }
}

extern "C" void kernel_launch(void* const* d_in, const int* in_sizes, int n_in,
                              void* d_out, int out_size, void* d_ws, size_t ws_size,
                              hipStream_t stream) {
    const float* xyz1 = (const float*)d_in[0];
    const float* xyz2 = (const float*)d_in[1];
    float* out = (float*)d_out;
    float* pmins = (float*)d_ws;

    chamfer_min<<<(BB * NN / (P * 256)) * SPLIT, 256, 0, stream>>>(xyz1, xyz2, pmins, out);
    chamfer_reduce<<<(BB * NN) / 256, 256, 0, stream>>>(pmins, out);
}